// Round 7
// baseline (248.847 us; speedup 1.0000x reference)
//
#include <hip/hip_runtime.h>

// VQ-VAE quantization: single-sweep bf16-MFMA prefilter + exact fp32 rescore.
// Round 7: fix r6's staging hazard. Per-wave 3-deep circular LDS buffer:
// iter t reads buf[t%3], stages tile t+2 into buf[(t+2)%3] (last read at
// iter t-1 -> full-iteration gap kills the WAR race and any scheduler hoist).
// Counted s_waitcnt vmcnt(3) (3 VMEM/iter: 2 global_load_lds + 1 h load).
// XOR-swizzled LDS (linear dest + inverse-swizzled global src + swizzled
// ds_read) kills the 16-way stride-128B bank conflict. LISTCAP restored to
// r5-validated 4096. Block = 64 points, 4 waves; wave w owns codes
// [w*1024, w*1024+1024).

#define NPTS    65536
#define CDIM    64
#define KCODES  4096
#define WAVES   4
#define KPW     (KCODES / WAVES)   // 1024 codes per wave
#define TILES   (KPW / 16)         // 64 tiles of 16 codes
#define NBUF    3
#define LISTCAP 4096
#define DELTA   0.25f

typedef __attribute__((ext_vector_type(8))) short short8;
typedef __attribute__((ext_vector_type(4))) float f32x4;

__device__ __forceinline__ unsigned short f2bf(float x) {
    unsigned u = __float_as_uint(x);
    return (unsigned short)((u + 0x7FFFu + ((u >> 16) & 1u)) >> 16);  // RNE
}

__device__ __forceinline__ void gload_lds16(const void* g, void* l) {
    __builtin_amdgcn_global_load_lds(
        (const __attribute__((address_space(1))) unsigned*)g,
        (__attribute__((address_space(3))) unsigned*)l, 16, 0, 0);
}

// cb fp32 -> bf16 copy + h[k] = 0.5*||e_k||^2
__global__ __launch_bounds__(256) void vq_prep(const float* __restrict__ cb,
                                               short* __restrict__ cbb,
                                               float* __restrict__ h) {
    int k = blockIdx.x * 256 + threadIdx.x;
    const float4* p = reinterpret_cast<const float4*>(cb + (size_t)k * CDIM);
    float s0 = 0.f, s1 = 0.f, s2 = 0.f, s3 = 0.f;
#pragma unroll
    for (int i = 0; i < 16; i += 2) {
        float4 va = p[i], vb = p[i + 1];
        s0 = fmaf(va.x, va.x, s0); s1 = fmaf(va.y, va.y, s1);
        s2 = fmaf(va.z, va.z, s2); s3 = fmaf(va.w, va.w, s3);
        s0 = fmaf(vb.x, vb.x, s0); s1 = fmaf(vb.y, vb.y, s1);
        s2 = fmaf(vb.z, vb.z, s2); s3 = fmaf(vb.w, vb.w, s3);
        short8 o;
        o[0] = (short)f2bf(va.x); o[1] = (short)f2bf(va.y);
        o[2] = (short)f2bf(va.z); o[3] = (short)f2bf(va.w);
        o[4] = (short)f2bf(vb.x); o[5] = (short)f2bf(vb.y);
        o[6] = (short)f2bf(vb.z); o[7] = (short)f2bf(vb.w);
        *reinterpret_cast<short8*>(cbb + (size_t)k * CDIM + i * 4) = o;
    }
    h[k] = 0.5f * ((s0 + s1) + (s2 + s3));
}

__global__ __launch_bounds__(256) void vq_main(const float* __restrict__ enc,
                                               const float* __restrict__ cbf,
                                               const short* __restrict__ cbb,
                                               const float* __restrict__ h,
                                               float* __restrict__ out) {
    __shared__ short bstage[WAVES][NBUF][1024];   // per-wave 3x2KB circular buffer
    __shared__ unsigned list[LISTCAP];
    __shared__ unsigned long long mkey[64];
    __shared__ unsigned lcnt;

    const int tid  = threadIdx.x;
    const int wid  = tid >> 6, lane = tid & 63;
    const int lrow = lane & 15, lseg = lane >> 4;
    const int pbase = blockIdx.x * 64;     // 64 points per block
    const int k0 = wid * KPW;              // this wave's code slice

    if (tid == 0) lcnt = 0;
    if (tid < 64) mkey[tid] = ~0ull;

    // ---- A fragments: the block's 64 points as bf16 ----
    // 16x16x32 A layout: row = lane&15, k = (lane>>4)*8 + e (+32 per kk)
    short8 afr[4][2];
#pragma unroll
    for (int rt = 0; rt < 4; ++rt)
#pragma unroll
        for (int kk = 0; kk < 2; ++kk) {
            const float4* xp = reinterpret_cast<const float4*>(
                enc + (size_t)(pbase + rt * 16 + lrow) * CDIM + kk * 32 + lseg * 8);
            float4 v0 = xp[0], v1 = xp[1];
            short8 a;
            a[0] = (short)f2bf(v0.x); a[1] = (short)f2bf(v0.y);
            a[2] = (short)f2bf(v0.z); a[3] = (short)f2bf(v0.w);
            a[4] = (short)f2bf(v1.x); a[5] = (short)f2bf(v1.y);
            a[6] = (short)f2bf(v1.z); a[7] = (short)f2bf(v1.w);
            afr[rt][kk] = a;
        }
    __syncthreads();   // lcnt/mkey init visible before any push

    // bthr[rt][i] tracks (running row max) - DELTA. Push if s >= bthr.
    f32x4 bthr[4];
#pragma unroll
    for (int rt = 0; rt < 4; ++rt)
#pragma unroll
        for (int i = 0; i < 4; ++i) bthr[rt][i] = -__builtin_inff();

    // ---- seed: tiles 62,63 via plain register loads, no push ----
#pragma unroll
    for (int sct = TILES - 2; sct < TILES; ++sct) {
        int code = k0 + sct * 16 + lrow;
        const short* base = cbb + (size_t)code * CDIM + lseg * 8;
        short8 b0 = *reinterpret_cast<const short8*>(base);
        short8 b1 = *reinterpret_cast<const short8*>(base + 32);
        float hc = h[code];
        f32x4 acc[4];
#pragma unroll
        for (int rt = 0; rt < 4; ++rt) { acc[rt][0] = -hc; acc[rt][1] = -hc; acc[rt][2] = -hc; acc[rt][3] = -hc; }
#pragma unroll
        for (int rt = 0; rt < 4; ++rt)
            acc[rt] = __builtin_amdgcn_mfma_f32_16x16x32_bf16(afr[rt][0], b0, acc[rt], 0, 0, 0);
#pragma unroll
        for (int rt = 0; rt < 4; ++rt)
            acc[rt] = __builtin_amdgcn_mfma_f32_16x16x32_bf16(afr[rt][1], b1, acc[rt], 0, 0, 0);
#pragma unroll
        for (int rt = 0; rt < 4; ++rt)
#pragma unroll
            for (int i = 0; i < 4; ++i) bthr[rt][i] = fmaxf(bthr[rt][i], acc[rt][i] - DELTA);
    }
#pragma unroll
    for (int m = 1; m <= 8; m <<= 1)
#pragma unroll
        for (int rt = 0; rt < 4; ++rt)
#pragma unroll
            for (int i = 0; i < 4; ++i)
                bthr[rt][i] = fmaxf(bthr[rt][i], __shfl_xor(bthr[rt][i], m, 64));

    // ---- async staged main sweep (3-deep circular buffer) ----
    char* bb = (char*)&bstage[wid][0][0];

    // Stage tile t (16 codes = 2KB) into buf. LDS dest is linear (HW adds
    // lane*16); global source is inverse-swizzled so the swizzled ds_read
    // retrieves correct data (both-sides-or-neither rule).
    auto stageT = [&](int t, int buf) {
        const char* g = (const char*)(cbb + (size_t)(k0 + t * 16) * CDIM);
#pragma unroll
        for (int j = 0; j < 2; ++j) {
            unsigned lw = (unsigned)j * 1024u + (unsigned)lane * 16u;
            unsigned src = lw ^ (((lw >> 7) & 7u) << 4);
            gload_lds16(g + src, bb + buf * 2048 + j * 1024);
        }
    };

    asm volatile("" ::: "memory");   // fence: prologue stages issue after seed drains
    stageT(0, 0);
    float h0 = h[k0 + lrow];
    asm volatile("" ::: "memory");
    stageT(1, 1);
    float h1 = h[k0 + 16 + lrow];
    // outstanding VMEM: [stage0(2)+h0] [stage1(2)+h1] = 6

    const unsigned swz = ((unsigned)(lrow & 7)) << 4;
    const unsigned roff0 = ((unsigned)(lrow * 128 + lseg * 16)) ^ swz;
    const unsigned roff1 = ((unsigned)(lrow * 128 + 64 + lseg * 16)) ^ swz;

    int bufR = 0;
    for (int t = 0; t < TILES; ++t) {
        // complete tile t's group (oldest 3); keep tile t+1's 3 in flight
        asm volatile("s_waitcnt vmcnt(3)" ::: "memory");
        __builtin_amdgcn_sched_barrier(0);
        const char* rb = bb + bufR * 2048;
        short8 b0 = *reinterpret_cast<const short8*>(rb + roff0);
        short8 b1 = *reinterpret_cast<const short8*>(rb + roff1);
        float hc = h0;
        f32x4 acc[4];
#pragma unroll
        for (int rt = 0; rt < 4; ++rt) { acc[rt][0] = -hc; acc[rt][1] = -hc; acc[rt][2] = -hc; acc[rt][3] = -hc; }
#pragma unroll
        for (int rt = 0; rt < 4; ++rt)
            acc[rt] = __builtin_amdgcn_mfma_f32_16x16x32_bf16(afr[rt][0], b0, acc[rt], 0, 0, 0);
#pragma unroll
        for (int rt = 0; rt < 4; ++rt)
            acc[rt] = __builtin_amdgcn_mfma_f32_16x16x32_bf16(afr[rt][1], b1, acc[rt], 0, 0, 0);

        // prefetch tile t+2 into buf[(t+2)%3] — last read at iter t-1, so no
        // pending-read hazard. Tail restages (never re-read, keeps vmcnt counts).
        {
            int bufS = bufR + 2; if (bufS >= NBUF) bufS -= NBUF;
            const int tn = (t + 2 < TILES) ? t + 2 : t;
            stageT(tn, bufS);
            float hnew = h[k0 + tn * 16 + lrow];
            h0 = h1; h1 = hnew;
        }

        // epilogue: push band candidates, update running threshold
        const unsigned code = (unsigned)(k0 + t * 16 + lrow);
#pragma unroll
        for (int rt = 0; rt < 4; ++rt)
#pragma unroll
            for (int i = 0; i < 4; ++i) {
                float s = acc[rt][i];
                if (s >= bthr[rt][i]) {
                    unsigned row = (unsigned)(rt * 16 + lseg * 4 + i);  // C/D row map (m89)
                    unsigned pos = atomicAdd(&lcnt, 1u);
                    if (pos < LISTCAP) list[pos] = (row << 12) | code;
                }
                bthr[rt][i] = fmaxf(bthr[rt][i], s - DELTA);
            }

        if ((t & 7) == 7) {   // re-tighten threshold across the 16 col-lanes
#pragma unroll
            for (int m = 1; m <= 8; m <<= 1)
#pragma unroll
                for (int rt = 0; rt < 4; ++rt)
#pragma unroll
                    for (int i = 0; i < 4; ++i)
                        bthr[rt][i] = fmaxf(bthr[rt][i], __shfl_xor(bthr[rt][i], m, 64));
        }

        bufR = (bufR + 1 == NBUF) ? 0 : bufR + 1;
    }
    __syncthreads();

    // ---- exact fp32 rescore: 4 lanes per candidate (coalesced 256B) ----
    unsigned cnt = lcnt; if (cnt > LISTCAP) cnt = LISTCAP;
    for (unsigned t4 = tid; t4 < cnt * 4; t4 += 256) {
        unsigned t = t4 >> 2; int q = t4 & 3;
        unsigned e = list[t];
        int row = (int)(e >> 12), c = (int)(e & 4095u);
        const float4* xp = reinterpret_cast<const float4*>(enc + (size_t)(pbase + row) * CDIM) + q * 4;
        const float4* ep = reinterpret_cast<const float4*>(cbf + (size_t)c * CDIM) + q * 4;
        float a0 = 0.f, a1 = 0.f, a2 = 0.f, a3 = 0.f;
#pragma unroll
        for (int i = 0; i < 4; ++i) {
            float4 xv = xp[i], ev = ep[i];
            a0 = fmaf(xv.x, ev.x, a0); a1 = fmaf(xv.y, ev.y, a1);
            a2 = fmaf(xv.z, ev.z, a2); a3 = fmaf(xv.w, ev.w, a3);
        }
        float p = (a0 + a1) + (a2 + a3);
        p += __shfl_xor(p, 1, 64);
        p += __shfl_xor(p, 2, 64);               // full dot in all 4 lanes
        if (q == 0) {
            float d2 = fmaf(-2.f, p, 2.f * h[c]);     // esq - 2*dot (bit-identical everywhere)
            unsigned bb2 = __float_as_uint(d2);
            unsigned ord = bb2 ^ (unsigned)(((int)bb2 >> 31) | 0x80000000);  // monotonic
            atomicMin(&mkey[row], ((unsigned long long)ord << 32) | (unsigned)c);
        }
    }
    __syncthreads();

    // ---- finalize: gather winner rows (4 threads per point) + idx ----
    {
        int p = tid >> 2, q = tid & 3;
        int c = (int)(mkey[p] & 4095u);
        const float4* ep = reinterpret_cast<const float4*>(cbf + (size_t)c * CDIM) + q * 4;
        float4* op = reinterpret_cast<float4*>(out + (size_t)(pbase + p) * CDIM) + q * 4;
#pragma unroll
        for (int i = 0; i < 4; ++i) op[i] = ep[i];
        if (tid < 64)
            out[(size_t)NPTS * CDIM + pbase + tid] = (float)(mkey[tid] & 4095u);
    }
}

extern "C" void kernel_launch(void* const* d_in, const int* in_sizes, int n_in,
                              void* d_out, int out_size, void* d_ws, size_t ws_size,
                              hipStream_t stream) {
    const float* enc = (const float*)d_in[0];
    const float* cb  = (const float*)d_in[1];
    float* out = (float*)d_out;

    // ws: cbb bf16[4096*64] (512KB) | h fp32[4096] (16KB)
    short* cbb = (short*)d_ws;
    float* hws = (float*)(cbb + (size_t)KCODES * CDIM);

    vq_prep<<<KCODES / 256, 256, 0, stream>>>(cb, cbb, hws);
    vq_main<<<NPTS / 64, 256, 0, stream>>>(enc, cb, cbb, hws, out);
}